// Round 1
// 399.538 us; speedup vs baseline: 1.0093x; 1.0093x over previous
//
#include <hip/hip_runtime.h>
#include <hip/hip_bf16.h>

typedef __hip_bfloat16 bf16;
typedef __attribute__((ext_vector_type(8))) short bf16x8;   // 8 bf16 = 4 VGPR
typedef __attribute__((ext_vector_type(4))) float f32x4;

#define N_NODES   131072
#define N_GRAPHS  4096
#define FIN       256
#define FH        512
#define NPAD      176     // 164 padded to 11*16
#define NREAL     164

// ---------- workspace layout (bytes) ----------
#define OFF_XB     0UL            // bf16 131072x256 = 67,108,864
#define OFF_XENDB  67108864UL     // bf16 4096x256   =  2,097,152
#define OFF_W1A    69206016UL     // bf16 512x256    =    262,144
#define OFF_BCAT   69468160UL     // bf16 1024x256   =    524,288
#define OFF_WXB    69992448UL     // bf16 176x512    =    180,224
#define OFF_STATS  70172672UL     // f32  4x512      =      8,192
#define OFF_XXE    70180864UL     // f32  4096
#define OFF_CCAT   70197248UL     // f32  4096x1024  = 16,777,216
#define OFF_H      86974464UL     // bf16 131072x512 = 134,217,728
// total ~211 MB

__device__ __forceinline__ void gld_lds16(const void* g, void* l) {
  __builtin_amdgcn_global_load_lds(
      (const __attribute__((address_space(1))) void*)g,
      (__attribute__((address_space(3))) void*)l, 16, 0, 0);
}

__device__ __forceinline__ float bf2f(unsigned short u) {
  unsigned int x = ((unsigned int)u) << 16; float f;
  __builtin_memcpy(&f, &x, 4); return f;
}
__device__ __forceinline__ unsigned short f2bf(float f) {
  bf16 h = __float2bfloat16(f); unsigned short u;
  __builtin_memcpy(&u, &h, 2); return u;
}

// ---------- K0: weight casts + zero stats ----------
__global__ __launch_bounds__(256) void k_wcast(
    const float* __restrict__ W_h, const float* __restrict__ W_ht,
    const float* __restrict__ W_x,
    bf16* __restrict__ W1a, bf16* __restrict__ Bcat, bf16* __restrict__ Wxb,
    float* __restrict__ stats)
{
  int i = blockIdx.x * 256 + threadIdx.x;            // grid 1024 -> 262144
  if (i < 2048) stats[i] = 0.f;                      // s1m,s2m,s1e,s2e
  if (i < 512 * 512) {
    int of = i >> 9, ic = i & 511;
    float v = W_h[i];
    if (ic < 256) W1a[of * 256 + ic] = __float2bfloat16(v);
    else          Bcat[of * 256 + (ic - 256)] = __float2bfloat16(v);
  }
  if (i < 512 * 256) Bcat[512 * 256 + i] = __float2bfloat16(W_ht[i]);
  if (i < NPAD * 512) {
    int n = i >> 9;
    Wxb[i] = (n < NREAL) ? __float2bfloat16(W_x[i]) : __float2bfloat16(0.f);
  }
}

// ---------- K1: per-graph mean of X + bf16 cast of X (fused) ----------
__global__ __launch_bounds__(256) void k_xend(
    const float* __restrict__ X, const int* __restrict__ NX,
    bf16* __restrict__ Xb, bf16* __restrict__ X_endb)
{
  int g = blockIdx.x;                 // 4096
  int t = threadIdx.x;
  int cg = t & 63;                    // cols cg*4..+3
  int rg = t >> 6;                    // rows rg*8..+7
  const float* Xg = X + (long)g * 32 * FIN;
  bf16* Xbg = Xb + (long)g * 32 * FIN;
  float4 s = {0.f, 0.f, 0.f, 0.f};
  #pragma unroll
  for (int r = 0; r < 8; ++r) {
    int off = (rg * 8 + r) * FIN + cg * 4;
    float4 v = *(const float4*)(Xg + off);
    s.x += v.x; s.y += v.y; s.z += v.z; s.w += v.w;
    ushort4 u = {f2bf(v.x), f2bf(v.y), f2bf(v.z), f2bf(v.w)};
    *(ushort4*)(Xbg + off) = u;
  }
  __shared__ float4 red[256];
  red[t] = s;
  __syncthreads();
  if (t < 64) {
    float4 a = red[t], b = red[t + 64], c = red[t + 128], d = red[t + 192];
    float inv = 1.f / (float)NX[g];
    float4 m = {(a.x + b.x + c.x + d.x) * inv, (a.y + b.y + c.y + d.y) * inv,
                (a.z + b.z + c.z + d.z) * inv, (a.w + b.w + c.w + d.w) * inv};
    ushort4 u = {f2bf(m.x), f2bf(m.y), f2bf(m.z), f2bf(m.w)};
    *(ushort4*)(X_endb + (long)g * FIN + t * 4) = u;
  }
}

// ---------- GEMM0: Ccat = X_endb @ [W1b; W_ht]^T  (M=4096,N=1024,K=256) ------
// + fused column stats for cols 512..1023 (the Hend half)
__global__ __launch_bounds__(256, 2) void gemm0(
    const bf16* __restrict__ A, const bf16* __restrict__ B,
    float* __restrict__ Cout, float* __restrict__ s1e, float* __restrict__ s2e)
{
  const int bid = blockIdx.x;                 // 256
  const int blkM = bid >> 3, blkN = bid & 7;
  const int tid = threadIdx.x;
  const int w = tid >> 6, lane = tid & 63;
  const int wm = w >> 1, wn = w & 1;

  __shared__ __align__(16) bf16 lA[128 * 32];
  __shared__ __align__(16) bf16 lB[128 * 32];
  __shared__ float sred[2][2][128];

  f32x4 acc[4][4] = {};
  const int rS = lane >> 2;
  const int cS = (lane & 3) * 8;
  const long baseA = (long)blkM * 128;
  const long baseB = (long)blkN * 128;

  for (int kk = 0; kk < FIN; kk += 32) {
    #pragma unroll
    for (int c = 0; c < 2; ++c) {
      int chunk = 2 * w + c;
      gld_lds16(A + (baseA + chunk * 16 + rS) * FIN + kk + cS, &lA[chunk * 16 * 32]);
      gld_lds16(B + (baseB + chunk * 16 + rS) * FIN + kk + cS, &lB[chunk * 16 * 32]);
    }
    __syncthreads();
    bf16x8 a8[4], b8[4];
    #pragma unroll
    for (int t = 0; t < 4; ++t) {
      a8[t] = *(const bf16x8*)&lA[(wm * 64 + t * 16 + (lane & 15)) * 32 + (lane >> 4) * 8];
      b8[t] = *(const bf16x8*)&lB[(wn * 64 + t * 16 + (lane & 15)) * 32 + (lane >> 4) * 8];
    }
    #pragma unroll
    for (int tm = 0; tm < 4; ++tm)
      #pragma unroll
      for (int tn = 0; tn < 4; ++tn)
        acc[tm][tn] = __builtin_amdgcn_mfma_f32_16x16x32_bf16(a8[tm], b8[tn], acc[tm][tn], 0, 0, 0);
    __syncthreads();
  }

  const int rowq = (lane >> 4) * 4;
  const int coll = lane & 15;
  float p1[4] = {0.f, 0.f, 0.f, 0.f}, p2[4] = {0.f, 0.f, 0.f, 0.f};
  #pragma unroll
  for (int tm = 0; tm < 4; ++tm)
    #pragma unroll
    for (int tn = 0; tn < 4; ++tn)
      #pragma unroll
      for (int r = 0; r < 4; ++r) {
        long row = baseA + wm * 64 + tm * 16 + rowq + r;
        int col = (int)baseB + wn * 64 + tn * 16 + coll;
        float v = acc[tm][tn][r];
        Cout[row * 1024 + col] = v;
        p1[tn] += v; p2[tn] += v * v;
      }

  if (blkN >= 4) {
    #pragma unroll
    for (int tn = 0; tn < 4; ++tn) {
      float q1 = p1[tn], q2 = p2[tn];
      q1 += __shfl_xor(q1, 16); q1 += __shfl_xor(q1, 32);
      q2 += __shfl_xor(q2, 16); q2 += __shfl_xor(q2, 32);
      if (lane < 16) {
        sred[wm][0][wn * 64 + tn * 16 + lane] = q1;
        sred[wm][1][wn * 64 + tn * 16 + lane] = q2;
      }
    }
    __syncthreads();
    int st = tid >> 7, c = tid & 127;
    float v = sred[0][st][c] + sred[1][st][c];
    atomicAdd((st ? s2e : s1e) + (blkN - 4) * 128 + c, v);
  }
}

// ---------- K3: end path, folded finalize ----------
__global__ __launch_bounds__(256) void k_xxend(
    const float* __restrict__ Ccat, const float* __restrict__ s1e,
    const float* __restrict__ s2e, const float* __restrict__ g_ht,
    const float* __restrict__ b_ht, const float* __restrict__ Wxt,
    const float* __restrict__ bxt, float* __restrict__ Xxe)
{
  __shared__ float aL[512], cL[512];
  int tid = threadIdx.x;
  #pragma unroll
  for (int i = tid; i < 512; i += 256) {
    float mean = s1e[i] * 2.44140625e-4f;
    float var = s2e[i] * 2.44140625e-4f - mean * mean;
    float a = g_ht[i] / sqrtf(var + 1e-5f);
    aL[i] = a; cL[i] = b_ht[i] - mean * a;
  }
  __syncthreads();
  int w = tid >> 6, lane = tid & 63;
  int g = blockIdx.x * 4 + w;          // grid 1024
  const float* h = Ccat + (long)g * 1024 + 512;
  float acc = 0.f;
  #pragma unroll
  for (int i = 0; i < 8; ++i) {
    int j = lane + i * 64;
    float x = fmaxf(aL[j] * h[j] + cL[j], 0.f);
    acc += x * Wxt[j];
  }
  #pragma unroll
  for (int off = 32; off; off >>= 1) acc += __shfl_xor(acc, off);
  if (lane == 0) Xxe[g] = expf(acc + bxt[0]);
}

// ---------- GEMM1 v2: W1a-half persistent in LDS, A streamed via vmcnt ring --
// Grid 256 x 512 threads (8 waves, 1 block/CU).
// Block: nhalf = bid&1 (256 cols of W1a), mgrp = bid>>1 (1024 rows = 8 tiles
// of 128).  LDS: lW [8 kstep][256 col][32 k] = 128 KB loaded ONCE;
// lA = 3-buffer ring of [128 row][32 k] (8 KB each).  Waves 2M x 4N,
// wave-tile 64x64, acc 4x4.  Counted s_waitcnt vmcnt(1) + raw s_barrier per
// step (T3/T4); full vmcnt(0) drain only once per M-tile, BEFORE the
// epilogue stores so stores are always older than the next counted wait.
// Column stats accumulated in registers across all 8 tiles, one atomic set
// per block at the end.
#define G1_STEP(MT, KS, WAIT, BAR)                                             \
  {                                                                            \
    if (WAIT) asm volatile("s_waitcnt vmcnt(1)" ::: "memory");                 \
    if (BAR) { __builtin_amdgcn_s_barrier();                                   \
               asm volatile("" ::: "memory"); }                                \
    int s2_ = (MT) * 8 + (KS) + 2; if (s2_ > 63) s2_ = 63;                     \
    gld_lds16(Xb + (rowbase + (long)(s2_ >> 3) * 128 + w * 16 + rS) * FIN      \
                 + (s2_ & 7) * 32 + cS,                                        \
              &lAf[ao2 + w * 512]);                                            \
    if ((KS) == 0) {                                                           \
      long gb_ = ((long)(mgrp * 8 + (MT))) * 4 + wm * 2;                       \
      _Pragma("unroll")                                                        \
      for (int a_ = 0; a_ < 2; ++a_)                                           \
        _Pragma("unroll")                                                      \
        for (int j_ = 0; j_ < 4; ++j_)                                         \
          ct[a_][j_] = Ccat[(gb_ + a_) * 1024 + nhalf * 256 + wn * 64          \
                            + j_ * 16 + coll];                                 \
    }                                                                          \
    bf16x8 a8_[4], b8_[4];                                                     \
    _Pragma("unroll")                                                          \
    for (int t_ = 0; t_ < 4; ++t_)                                             \
      a8_[t_] = *(const bf16x8*)&lAf[ao0 + (wm * 64 + t_ * 16 + coll) * 32     \
                                     + hi * 8];                                \
    _Pragma("unroll")                                                          \
    for (int j_ = 0; j_ < 4; ++j_)                                             \
      b8_[j_] = *(const bf16x8*)&lW[((KS) * 256 + wn * 64 + j_ * 16 + coll)    \
                                    * 32 + hi * 8];                            \
    _Pragma("unroll")                                                          \
    for (int t_ = 0; t_ < 4; ++t_)                                             \
      _Pragma("unroll")                                                        \
      for (int j_ = 0; j_ < 4; ++j_)                                           \
        acc[t_][j_] = __builtin_amdgcn_mfma_f32_16x16x32_bf16(                 \
            a8_[t_], b8_[j_], acc[t_][j_], 0, 0, 0);                           \
    unsigned tmp_ = ao0; ao0 = ao1; ao1 = ao2; ao2 = tmp_;                     \
  }

__global__ __launch_bounds__(512) void gemm1(
    const bf16* __restrict__ Xb, const bf16* __restrict__ W1a,
    const float* __restrict__ Ccat, bf16* __restrict__ H,
    float* __restrict__ s1m, float* __restrict__ s2m)
{
  const int bid = blockIdx.x;            // 256
  const int nhalf = bid & 1;
  const int mgrp  = bid >> 1;            // 0..127
  const int tid = threadIdx.x;
  const int w = tid >> 6, lane = tid & 63;
  const int wm = w >> 2, wn = w & 3;     // 2M x 4N
  const int rS = lane >> 2;              // staging row-in-chunk
  const int cS = (lane & 3) * 8;         // staging k-offset (elements)
  const int hi = lane >> 4;              // fragment k-group
  const int coll = lane & 15;
  const int rowq = hi * 4;

  __shared__ __align__(16) bf16 lW[8 * 256 * 32];   // 128 KB, [ks][col][32]
  __shared__ __align__(16) bf16 lAf[3 * 128 * 32];  // 24 KB ring

  // ---- prologue: stage W half (16 x 1KB chunks per wave) + A steps 0,1 ----
  const long wrow = (long)nhalf * 256;
  #pragma unroll
  for (int c0 = 0; c0 < 16; ++c0) {
    int c = c0 * 8 + w;                  // 128 chunks: [ks = c>>4][colgrp = c&15]
    gld_lds16(W1a + (wrow + (c & 15) * 16 + rS) * FIN + (c >> 4) * 32 + cS,
              &lW[c * 512]);
  }
  const long rowbase = (long)mgrp * 1024;
  gld_lds16(Xb + (rowbase + w * 16 + rS) * FIN + 0  + cS, &lAf[0    + w * 512]);
  gld_lds16(Xb + (rowbase + w * 16 + rS) * FIN + 32 + cS, &lAf[4096 + w * 512]);
  asm volatile("s_waitcnt vmcnt(0)" ::: "memory");
  __builtin_amdgcn_s_barrier();
  asm volatile("" ::: "memory");

  f32x4 acc[4][4] = {};
  float p1[4] = {0.f, 0.f, 0.f, 0.f}, p2[4] = {0.f, 0.f, 0.f, 0.f};
  unsigned ao0 = 0, ao1 = 4096, ao2 = 8192;

  #pragma unroll 1
  for (int mt = 0; mt < 8; ++mt) {
    float ct[2][4];
    G1_STEP(mt, 0, 0, 0)   // buffers 0,1 guaranteed by tile-end/prologue drain
    G1_STEP(mt, 1, 0, 1)   // barrier only (WAR on ring slot)
    G1_STEP(mt, 2, 1, 1)
    G1_STEP(mt, 3, 1, 1)
    G1_STEP(mt, 4, 1, 1)
    G1_STEP(mt, 5, 1, 1)
    G1_STEP(mt, 6, 1, 1)
    G1_STEP(mt, 7, 1, 1)
    // tile-end drain: next tile's 2 prefetches landed; stores issued AFTER
    // this point are older than every subsequent counted wait.
    asm volatile("s_waitcnt vmcnt(0)" ::: "memory");
    __builtin_amdgcn_s_barrier();
    asm volatile("" ::: "memory");

    const long rtile = rowbase + (long)mt * 128 + wm * 64;
    #pragma unroll
    for (int t = 0; t < 4; ++t) {
      #pragma unroll
      for (int j = 0; j < 4; ++j) {
        int col = nhalf * 256 + wn * 64 + j * 16 + coll;
        #pragma unroll
        for (int r = 0; r < 4; ++r) {
          float h = acc[t][j][r] + ct[t >> 1][j];
          H[(rtile + t * 16 + rowq + r) * FH + col] = __float2bfloat16(h);
          p1[j] += h; p2[j] += h * h;
        }
        acc[t][j][0] = 0.f; acc[t][j][1] = 0.f;
        acc[t][j][2] = 0.f; acc[t][j][3] = 0.f;
      }
    }
  }

  #pragma unroll
  for (int j = 0; j < 4; ++j) {
    float q1 = p1[j], q2 = p2[j];
    q1 += __shfl_xor(q1, 16); q1 += __shfl_xor(q1, 32);
    q2 += __shfl_xor(q2, 16); q2 += __shfl_xor(q2, 32);
    if (lane < 16) {
      atomicAdd(s1m + nhalf * 256 + wn * 64 + j * 16 + lane, q1);
      atomicAdd(s2m + nhalf * 256 + wn * 64 + j * 16 + lane, q2);
    }
  }
}

// ---------- GEMM2: fused BN-finalize + relu-transform + exp/graph-softmax ----
__global__ __launch_bounds__(256, 2) void gemm2(
    const bf16* __restrict__ Hraw, const bf16* __restrict__ Wxb,
    const float* __restrict__ s1m, const float* __restrict__ s2m,
    const float* __restrict__ g_h, const float* __restrict__ b_h,
    const float* __restrict__ b_x, const float* __restrict__ Xxe,
    float* __restrict__ outA, float* __restrict__ outC, float* __restrict__ outE)
{
  const int blk = blockIdx.x;          // 1024
  const int tid = threadIdx.x;
  const int w = tid >> 6, lane = tid & 63;

  __shared__ __align__(16) bf16 lA[128 * 32];
  __shared__ __align__(16) bf16 lB[NPAD * 32];
  __shared__ float aL[512], cL[512];

  #pragma unroll
  for (int i = tid; i < 512; i += 256) {
    float mean = s1m[i] * 7.62939453125e-6f;
    float var = s2m[i] * 7.62939453125e-6f - mean * mean;
    float a = g_h[i] / sqrtf(var + 1e-5f);
    aL[i] = a; cL[i] = b_h[i] - mean * a;
  }
  __syncthreads();

  f32x4 acc[2][11] = {};
  const int rS = lane >> 2;
  const int cS = (lane & 3) * 8;
  const long baseRow = (long)blk * 128;

  for (int kk = 0; kk < FH; kk += 32) {
    for (int o = w; o < 11; o += 4)
      gld_lds16(Wxb + (o * 16 + rS) * FH + kk + cS, &lB[o * 16 * 32]);

    // A: load raw H, apply relu(a*h+c), ds_write
    f32x4 a0 = *(const f32x4*)&aL[kk + cS];
    f32x4 a1 = *(const f32x4*)&aL[kk + cS + 4];
    f32x4 c0 = *(const f32x4*)&cL[kk + cS];
    f32x4 c1 = *(const f32x4*)&cL[kk + cS + 4];
    #pragma unroll
    for (int c = 0; c < 2; ++c) {
      int chunk = 2 * w + c;
      uint4 raw = *(const uint4*)(Hraw + (baseRow + chunk * 16 + rS) * FH + kk + cS);
      unsigned short* u = (unsigned short*)&raw;
      #pragma unroll
      for (int j = 0; j < 4; ++j) {
        float v = bf2f(u[j]);
        u[j] = f2bf(fmaxf(a0[j] * v + c0[j], 0.f));
      }
      #pragma unroll
      for (int j = 0; j < 4; ++j) {
        float v = bf2f(u[4 + j]);
        u[4 + j] = f2bf(fmaxf(a1[j] * v + c1[j], 0.f));
      }
      *(uint4*)&lA[(chunk * 16 + rS) * 32 + cS] = raw;
    }
    __syncthreads();

    bf16x8 a8[2], b8[11];
    #pragma unroll
    for (int t = 0; t < 2; ++t)
      a8[t] = *(const bf16x8*)&lA[(w * 32 + t * 16 + (lane & 15)) * 32 + (lane >> 4) * 8];
    #pragma unroll
    for (int t = 0; t < 11; ++t)
      b8[t] = *(const bf16x8*)&lB[(t * 16 + (lane & 15)) * 32 + (lane >> 4) * 8];
    #pragma unroll
    for (int tm = 0; tm < 2; ++tm)
      #pragma unroll
      for (int tn = 0; tn < 11; ++tn)
        acc[tm][tn] = __builtin_amdgcn_mfma_f32_16x16x32_bf16(a8[tm], b8[tn], acc[tm][tn], 0, 0, 0);
    __syncthreads();
  }

  const int rowq = (lane >> 4) * 4;
  const int coll = lane & 15;
  const int g = blk * 4 + w;
  float psum = 0.f;
  #pragma unroll
  for (int tn = 0; tn < 11; ++tn) {
    int col = tn * 16 + coll;
    bool valid = col < NREAL;
    float bx = valid ? b_x[col] : 0.f;
    #pragma unroll
    for (int tm = 0; tm < 2; ++tm)
      #pragma unroll
      for (int r = 0; r < 4; ++r) {
        float p = valid ? expf(acc[tm][tn][r] + bx) : 0.f;
        acc[tm][tn][r] = p;
        psum += p;
      }
  }
  #pragma unroll
  for (int off = 32; off; off >>= 1) psum += __shfl_xor(psum, off);
  float Xe = Xxe[g];
  float inv = 1.0f / (psum + Xe);
  if (lane == 0) outE[g] = Xe * inv;

  #pragma unroll
  for (int tn = 0; tn < 11; ++tn) {
    int col = tn * 16 + coll;
    if (col >= NREAL) continue;
    #pragma unroll
    for (int tm = 0; tm < 2; ++tm)
      #pragma unroll
      for (int r = 0; r < 4; ++r) {
        long row = baseRow + w * 32 + tm * 16 + rowq + r;
        float v = acc[tm][tn][r] * inv;
        if (col >= 4) outA[row * 160 + (col - 4)] = v;
        else          outC[row * 4 + col] = v;
      }
  }
}

extern "C" void kernel_launch(void* const* d_in, const int* in_sizes, int n_in,
                              void* d_out, int out_size, void* d_ws, size_t ws_size,
                              hipStream_t stream)
{
  const float* X    = (const float*)d_in[0];
  const int*   NX   = (const int*)d_in[1];      // int64 in ref -> int32 in harness
  const float* W_h  = (const float*)d_in[3];
  const float* g_h  = (const float*)d_in[4];
  const float* b_h  = (const float*)d_in[5];
  const float* W_ht = (const float*)d_in[6];
  const float* g_ht = (const float*)d_in[7];
  const float* b_ht = (const float*)d_in[8];
  const float* W_x  = (const float*)d_in[9];
  const float* b_x  = (const float*)d_in[10];
  const float* W_xt = (const float*)d_in[11];
  const float* b_xt = (const float*)d_in[12];

  char* ws = (char*)d_ws;
  bf16*  Xb    = (bf16*)(ws + OFF_XB);
  bf16*  X_endb= (bf16*)(ws + OFF_XENDB);
  bf16*  W1a   = (bf16*)(ws + OFF_W1A);
  bf16*  Bcat  = (bf16*)(ws + OFF_BCAT);
  bf16*  Wxb   = (bf16*)(ws + OFF_WXB);
  float* stats = (float*)(ws + OFF_STATS);
  float* s1m = stats, *s2m = stats + 512, *s1e = stats + 1024, *s2e = stats + 1536;
  float* Xxe   = (float*)(ws + OFF_XXE);
  float* Ccat  = (float*)(ws + OFF_CCAT);
  bf16*  H     = (bf16*)(ws + OFF_H);

  float* outA = (float*)d_out;                 // append: 131072*160
  float* outC = outA + (long)N_NODES * 160;    // connect: 131072*4
  float* outE = outC + (long)N_NODES * 4;      // end: 4096

  k_wcast<<<1024, 256, 0, stream>>>(W_h, W_ht, W_x, W1a, Bcat, Wxb, stats);
  k_xend<<<N_GRAPHS, 256, 0, stream>>>(X, NX, Xb, X_endb);
  gemm0<<<256, 256, 0, stream>>>(X_endb, Bcat, Ccat, s1e, s2e);
  k_xxend<<<1024, 256, 0, stream>>>(Ccat, s1e, s2e, g_ht, b_ht, W_xt, b_xt, Xxe);
  gemm1<<<256, 512, 0, stream>>>(Xb, W1a, Ccat, H, s1m, s2m);
  gemm2<<<1024, 256, 0, stream>>>(H, Wxb, s1m, s2m, g_h, b_h, b_x, Xxe, outA, outC, outE);
}

// Round 2
// 389.788 us; speedup vs baseline: 1.0345x; 1.0250x over previous
//
#include <hip/hip_runtime.h>
#include <hip/hip_bf16.h>

typedef __hip_bfloat16 bf16;
typedef __attribute__((ext_vector_type(8))) short bf16x8;   // 8 bf16 = 4 VGPR
typedef __attribute__((ext_vector_type(4))) float f32x4;

#define N_NODES   131072
#define N_GRAPHS  4096
#define FIN       256
#define FH        512
#define NPAD      176     // 164 padded to 11*16
#define NREAL     164

// ---------- workspace layout (bytes) ----------
#define OFF_XB     0UL            // bf16 131072x256 = 67,108,864
#define OFF_XENDB  67108864UL     // bf16 4096x256   =  2,097,152
#define OFF_W1A    69206016UL     // bf16 512x256    =    262,144
#define OFF_BCAT   69468160UL     // bf16 1024x256   =    524,288
#define OFF_WXB    69992448UL     // bf16 176x512    =    180,224
#define OFF_STATS  70172672UL     // f32  4x512      =      8,192
#define OFF_XXE    70180864UL     // f32  4096
#define OFF_CCAT   70197248UL     // f32  4096x1024  = 16,777,216
#define OFF_H      86974464UL     // bf16 131072x512 = 134,217,728
// total ~211 MB

__device__ __forceinline__ void gld_lds16(const void* g, void* l) {
  __builtin_amdgcn_global_load_lds(
      (const __attribute__((address_space(1))) void*)g,
      (__attribute__((address_space(3))) void*)l, 16, 0, 0);
}

__device__ __forceinline__ float bf2f(unsigned short u) {
  unsigned int x = ((unsigned int)u) << 16; float f;
  __builtin_memcpy(&f, &x, 4); return f;
}
__device__ __forceinline__ unsigned short f2bf(float f) {
  bf16 h = __float2bfloat16(f); unsigned short u;
  __builtin_memcpy(&u, &h, 2); return u;
}

// ---------- K0: weight casts + zero stats ----------
__global__ __launch_bounds__(256) void k_wcast(
    const float* __restrict__ W_h, const float* __restrict__ W_ht,
    const float* __restrict__ W_x,
    bf16* __restrict__ W1a, bf16* __restrict__ Bcat, bf16* __restrict__ Wxb,
    float* __restrict__ stats)
{
  int i = blockIdx.x * 256 + threadIdx.x;            // grid 1024 -> 262144
  if (i < 2048) stats[i] = 0.f;                      // s1m,s2m,s1e,s2e
  if (i < 512 * 512) {
    int of = i >> 9, ic = i & 511;
    float v = W_h[i];
    if (ic < 256) W1a[of * 256 + ic] = __float2bfloat16(v);
    else          Bcat[of * 256 + (ic - 256)] = __float2bfloat16(v);
  }
  if (i < 512 * 256) Bcat[512 * 256 + i] = __float2bfloat16(W_ht[i]);
  if (i < NPAD * 512) {
    int n = i >> 9;
    Wxb[i] = (n < NREAL) ? __float2bfloat16(W_x[i]) : __float2bfloat16(0.f);
  }
}

// ---------- K1: per-graph mean of X + bf16 cast of X (fused) ----------
__global__ __launch_bounds__(256) void k_xend(
    const float* __restrict__ X, const int* __restrict__ NX,
    bf16* __restrict__ Xb, bf16* __restrict__ X_endb)
{
  int g = blockIdx.x;                 // 4096
  int t = threadIdx.x;
  int cg = t & 63;                    // cols cg*4..+3
  int rg = t >> 6;                    // rows rg*8..+7
  const float* Xg = X + (long)g * 32 * FIN;
  bf16* Xbg = Xb + (long)g * 32 * FIN;
  float4 s = {0.f, 0.f, 0.f, 0.f};
  #pragma unroll
  for (int r = 0; r < 8; ++r) {
    int off = (rg * 8 + r) * FIN + cg * 4;
    float4 v = *(const float4*)(Xg + off);
    s.x += v.x; s.y += v.y; s.z += v.z; s.w += v.w;
    ushort4 u = {f2bf(v.x), f2bf(v.y), f2bf(v.z), f2bf(v.w)};
    *(ushort4*)(Xbg + off) = u;
  }
  __shared__ float4 red[256];
  red[t] = s;
  __syncthreads();
  if (t < 64) {
    float4 a = red[t], b = red[t + 64], c = red[t + 128], d = red[t + 192];
    float inv = 1.f / (float)NX[g];
    float4 m = {(a.x + b.x + c.x + d.x) * inv, (a.y + b.y + c.y + d.y) * inv,
                (a.z + b.z + c.z + d.z) * inv, (a.w + b.w + c.w + d.w) * inv};
    ushort4 u = {f2bf(m.x), f2bf(m.y), f2bf(m.z), f2bf(m.w)};
    *(ushort4*)(X_endb + (long)g * FIN + t * 4) = u;
  }
}

// ---------- GEMM0: Ccat = X_endb @ [W1b; W_ht]^T  (M=4096,N=1024,K=256) ------
// + fused column stats for cols 512..1023 (the Hend half)
__global__ __launch_bounds__(256, 2) void gemm0(
    const bf16* __restrict__ A, const bf16* __restrict__ B,
    float* __restrict__ Cout, float* __restrict__ s1e, float* __restrict__ s2e)
{
  const int bid = blockIdx.x;                 // 256
  const int blkM = bid >> 3, blkN = bid & 7;
  const int tid = threadIdx.x;
  const int w = tid >> 6, lane = tid & 63;
  const int wm = w >> 1, wn = w & 1;

  __shared__ __align__(16) bf16 lA[128 * 32];
  __shared__ __align__(16) bf16 lB[128 * 32];
  __shared__ float sred[2][2][128];

  f32x4 acc[4][4] = {};
  const int rS = lane >> 2;
  const int cS = (lane & 3) * 8;
  const long baseA = (long)blkM * 128;
  const long baseB = (long)blkN * 128;

  for (int kk = 0; kk < FIN; kk += 32) {
    #pragma unroll
    for (int c = 0; c < 2; ++c) {
      int chunk = 2 * w + c;
      gld_lds16(A + (baseA + chunk * 16 + rS) * FIN + kk + cS, &lA[chunk * 16 * 32]);
      gld_lds16(B + (baseB + chunk * 16 + rS) * FIN + kk + cS, &lB[chunk * 16 * 32]);
    }
    __syncthreads();
    bf16x8 a8[4], b8[4];
    #pragma unroll
    for (int t = 0; t < 4; ++t) {
      a8[t] = *(const bf16x8*)&lA[(wm * 64 + t * 16 + (lane & 15)) * 32 + (lane >> 4) * 8];
      b8[t] = *(const bf16x8*)&lB[(wn * 64 + t * 16 + (lane & 15)) * 32 + (lane >> 4) * 8];
    }
    #pragma unroll
    for (int tm = 0; tm < 4; ++tm)
      #pragma unroll
      for (int tn = 0; tn < 4; ++tn)
        acc[tm][tn] = __builtin_amdgcn_mfma_f32_16x16x32_bf16(a8[tm], b8[tn], acc[tm][tn], 0, 0, 0);
    __syncthreads();
  }

  const int rowq = (lane >> 4) * 4;
  const int coll = lane & 15;
  float p1[4] = {0.f, 0.f, 0.f, 0.f}, p2[4] = {0.f, 0.f, 0.f, 0.f};
  #pragma unroll
  for (int tm = 0; tm < 4; ++tm)
    #pragma unroll
    for (int tn = 0; tn < 4; ++tn)
      #pragma unroll
      for (int r = 0; r < 4; ++r) {
        long row = baseA + wm * 64 + tm * 16 + rowq + r;
        int col = (int)baseB + wn * 64 + tn * 16 + coll;
        float v = acc[tm][tn][r];
        Cout[row * 1024 + col] = v;
        p1[tn] += v; p2[tn] += v * v;
      }

  if (blkN >= 4) {
    #pragma unroll
    for (int tn = 0; tn < 4; ++tn) {
      float q1 = p1[tn], q2 = p2[tn];
      q1 += __shfl_xor(q1, 16); q1 += __shfl_xor(q1, 32);
      q2 += __shfl_xor(q2, 16); q2 += __shfl_xor(q2, 32);
      if (lane < 16) {
        sred[wm][0][wn * 64 + tn * 16 + lane] = q1;
        sred[wm][1][wn * 64 + tn * 16 + lane] = q2;
      }
    }
    __syncthreads();
    int st = tid >> 7, c = tid & 127;
    float v = sred[0][st][c] + sred[1][st][c];
    atomicAdd((st ? s2e : s1e) + (blkN - 4) * 128 + c, v);
  }
}

// ---------- K3: end path, folded finalize ----------
__global__ __launch_bounds__(256) void k_xxend(
    const float* __restrict__ Ccat, const float* __restrict__ s1e,
    const float* __restrict__ s2e, const float* __restrict__ g_ht,
    const float* __restrict__ b_ht, const float* __restrict__ Wxt,
    const float* __restrict__ bxt, float* __restrict__ Xxe)
{
  __shared__ float aL[512], cL[512];
  int tid = threadIdx.x;
  #pragma unroll
  for (int i = tid; i < 512; i += 256) {
    float mean = s1e[i] * 2.44140625e-4f;
    float var = s2e[i] * 2.44140625e-4f - mean * mean;
    float a = g_ht[i] / sqrtf(var + 1e-5f);
    aL[i] = a; cL[i] = b_ht[i] - mean * a;
  }
  __syncthreads();
  int w = tid >> 6, lane = tid & 63;
  int g = blockIdx.x * 4 + w;          // grid 1024
  const float* h = Ccat + (long)g * 1024 + 512;
  float acc = 0.f;
  #pragma unroll
  for (int i = 0; i < 8; ++i) {
    int j = lane + i * 64;
    float x = fmaxf(aL[j] * h[j] + cL[j], 0.f);
    acc += x * Wxt[j];
  }
  #pragma unroll
  for (int off = 32; off; off >>= 1) acc += __shfl_xor(acc, off);
  if (lane == 0) Xxe[g] = expf(acc + bxt[0]);
}

// ---------- GEMM1 v3: barrier-free; B in registers; private per-wave LDS ring
// Grid 256 x 512 threads (8 waves, 1 block/CU). Block owns 512 rows x 512 cols.
// Wave w owns cols w*64..+63: its whole B-panel (64 cols x K=256) lives in
// 128 VGPRs (b8[4][8]). A (64 rows x 32 k per step) is staged into a PRIVATE
// per-wave 4-slot LDS ring (8 x 16 KB = 128 KB) via global_load_lds, prefetch
// depth 2, self-paced with counted s_waitcnt vmcnt(N) -- NO barriers anywhere.
// vmcnt ledger (in-order counting; smaller N = stricter = always correct):
//   step u reads slot u&3 (its 4 gld issued at step u-2, 8 newer gld after it)
//   -> wait vmcnt(4) leaves only target-(u+1)'s 4 outstanding.
//   At ks 0/1 the 8 compiler-issued Ccat loads (tile top) sit between the
//   two in-flight gld batches -> vmcnt(12) keeps them + next-target in flight.
//   Tail steps issue clamped re-loads of step 63 into dead slots so the
//   outstanding count stays uniform.
__global__ __launch_bounds__(512) void gemm1(
    const bf16* __restrict__ Xb, const bf16* __restrict__ W1a,
    const float* __restrict__ Ccat, bf16* __restrict__ H,
    float* __restrict__ s1m, float* __restrict__ s2m)
{
  const int bid = blockIdx.x;            // 256
  const int tid = threadIdx.x;
  const int w = tid >> 6, lane = tid & 63;
  const int rS = lane >> 2;              // staging row-in-16-chunk
  const int cS = (lane & 3) * 8;         // staging k elem offset
  const int hi = lane >> 4;
  const int coll = lane & 15;

  __shared__ __align__(16) bf16 ring[8][4][2048];   // per-wave private ring

  // ---- B panel -> registers (64 cols x 256 K = 32 x bf16x8 = 128 VGPR) ----
  bf16x8 b8[4][8];
  #pragma unroll
  for (int j = 0; j < 4; ++j)
    #pragma unroll
    for (int ks = 0; ks < 8; ++ks)
      b8[j][ks] = *(const bf16x8*)(W1a + (w * 64 + j * 16 + coll) * FIN
                                   + ks * 32 + hi * 8);

  // ---- prologue: stage steps 0,1 into slots 0,1 ----
  const long rowbase = (long)bid * 512;
  #pragma unroll
  for (int s = 0; s < 2; ++s)
    #pragma unroll
    for (int c = 0; c < 4; ++c)
      gld_lds16(Xb + (rowbase + c * 16 + rS) * FIN + s * 32 + cS,
                &ring[w][s][c * 512]);

  f32x4 acc[4][4] = {};
  float p1[4] = {0.f, 0.f, 0.f, 0.f}, p2[4] = {0.f, 0.f, 0.f, 0.f};

  #pragma unroll 1
  for (int mt = 0; mt < 8; ++mt) {
    // Bterm for this tile's 2 graphs (compiler-managed loads; consumed at
    // epilogue ~8 steps later -- its own waitcnt is a free vmcnt(32))
    const long g0 = (rowbase >> 5) + mt * 2;
    float ct[2][4];
    #pragma unroll
    for (int a = 0; a < 2; ++a)
      #pragma unroll
      for (int j = 0; j < 4; ++j)
        ct[a][j] = Ccat[(g0 + a) * 1024 + w * 64 + j * 16 + coll];

    #pragma unroll
    for (int ks = 0; ks < 8; ++ks) {
      if (ks < 2) asm volatile("s_waitcnt vmcnt(12)" ::: "memory");
      else        asm volatile("s_waitcnt vmcnt(4)" ::: "memory");

      // prefetch step u+2 (clamped dummy re-load at the tail, lands in a
      // dead slot with identical bytes -> benign)
      {
        int tgt = mt * 8 + ks + 2; if (tgt > 63) tgt = 63;
        const bf16* src = Xb + (rowbase + (long)(tgt >> 3) * 64 + rS) * FIN
                          + (tgt & 7) * 32 + cS;
        #pragma unroll
        for (int c = 0; c < 4; ++c)
          gld_lds16(src + c * 16 * FIN, &ring[w][(ks + 2) & 3][c * 512]);
      }

      bf16x8 a8[4];
      #pragma unroll
      for (int t = 0; t < 4; ++t)
        a8[t] = *(const bf16x8*)&ring[w][ks & 3][(t * 16 + coll) * 32 + hi * 8];
      #pragma unroll
      for (int t = 0; t < 4; ++t)
        #pragma unroll
        for (int j = 0; j < 4; ++j)
          acc[t][j] = __builtin_amdgcn_mfma_f32_16x16x32_bf16(
              a8[t], b8[j][ks], acc[t][j], 0, 0, 0);
    }

    // ---- epilogue: registers only (no sync, no drain) ----
    const long rtile = rowbase + (long)mt * 64;
    #pragma unroll
    for (int t = 0; t < 4; ++t)
      #pragma unroll
      for (int j = 0; j < 4; ++j) {
        int col = w * 64 + j * 16 + coll;
        #pragma unroll
        for (int r = 0; r < 4; ++r) {
          float h = acc[t][j][r] + ct[t >> 1][j];
          H[(rtile + t * 16 + hi * 4 + r) * FH + col] = __float2bfloat16(h);
          p1[j] += h; p2[j] += h * h;
        }
        acc[t][j][0] = 0.f; acc[t][j][1] = 0.f;
        acc[t][j][2] = 0.f; acc[t][j][3] = 0.f;
      }
  }

  // ---- column stats: one atomic set per wave ----
  #pragma unroll
  for (int j = 0; j < 4; ++j) {
    float q1 = p1[j], q2 = p2[j];
    q1 += __shfl_xor(q1, 16); q1 += __shfl_xor(q1, 32);
    q2 += __shfl_xor(q2, 16); q2 += __shfl_xor(q2, 32);
    if (lane < 16) {
      atomicAdd(s1m + w * 64 + j * 16 + lane, q1);
      atomicAdd(s2m + w * 64 + j * 16 + lane, q2);
    }
  }
}

// ---------- GEMM2: fused BN-finalize + relu-transform + exp/graph-softmax ----
__global__ __launch_bounds__(256, 2) void gemm2(
    const bf16* __restrict__ Hraw, const bf16* __restrict__ Wxb,
    const float* __restrict__ s1m, const float* __restrict__ s2m,
    const float* __restrict__ g_h, const float* __restrict__ b_h,
    const float* __restrict__ b_x, const float* __restrict__ Xxe,
    float* __restrict__ outA, float* __restrict__ outC, float* __restrict__ outE)
{
  const int blk = blockIdx.x;          // 1024
  const int tid = threadIdx.x;
  const int w = tid >> 6, lane = tid & 63;

  __shared__ __align__(16) bf16 lA[128 * 32];
  __shared__ __align__(16) bf16 lB[NPAD * 32];
  __shared__ float aL[512], cL[512];

  #pragma unroll
  for (int i = tid; i < 512; i += 256) {
    float mean = s1m[i] * 7.62939453125e-6f;
    float var = s2m[i] * 7.62939453125e-6f - mean * mean;
    float a = g_h[i] / sqrtf(var + 1e-5f);
    aL[i] = a; cL[i] = b_h[i] - mean * a;
  }
  __syncthreads();

  f32x4 acc[2][11] = {};
  const int rS = lane >> 2;
  const int cS = (lane & 3) * 8;
  const long baseRow = (long)blk * 128;

  for (int kk = 0; kk < FH; kk += 32) {
    for (int o = w; o < 11; o += 4)
      gld_lds16(Wxb + (o * 16 + rS) * FH + kk + cS, &lB[o * 16 * 32]);

    // A: load raw H, apply relu(a*h+c), ds_write
    f32x4 a0 = *(const f32x4*)&aL[kk + cS];
    f32x4 a1 = *(const f32x4*)&aL[kk + cS + 4];
    f32x4 c0 = *(const f32x4*)&cL[kk + cS];
    f32x4 c1 = *(const f32x4*)&cL[kk + cS + 4];
    #pragma unroll
    for (int c = 0; c < 2; ++c) {
      int chunk = 2 * w + c;
      uint4 raw = *(const uint4*)(Hraw + (baseRow + chunk * 16 + rS) * FH + kk + cS);
      unsigned short* u = (unsigned short*)&raw;
      #pragma unroll
      for (int j = 0; j < 4; ++j) {
        float v = bf2f(u[j]);
        u[j] = f2bf(fmaxf(a0[j] * v + c0[j], 0.f));
      }
      #pragma unroll
      for (int j = 0; j < 4; ++j) {
        float v = bf2f(u[4 + j]);
        u[4 + j] = f2bf(fmaxf(a1[j] * v + c1[j], 0.f));
      }
      *(uint4*)&lA[(chunk * 16 + rS) * 32 + cS] = raw;
    }
    __syncthreads();

    bf16x8 a8[2], b8[11];
    #pragma unroll
    for (int t = 0; t < 2; ++t)
      a8[t] = *(const bf16x8*)&lA[(w * 32 + t * 16 + (lane & 15)) * 32 + (lane >> 4) * 8];
    #pragma unroll
    for (int t = 0; t < 11; ++t)
      b8[t] = *(const bf16x8*)&lB[(t * 16 + (lane & 15)) * 32 + (lane >> 4) * 8];
    #pragma unroll
    for (int tm = 0; tm < 2; ++tm)
      #pragma unroll
      for (int tn = 0; tn < 11; ++tn)
        acc[tm][tn] = __builtin_amdgcn_mfma_f32_16x16x32_bf16(a8[tm], b8[tn], acc[tm][tn], 0, 0, 0);
    __syncthreads();
  }

  const int rowq = (lane >> 4) * 4;
  const int coll = lane & 15;
  const int g = blk * 4 + w;
  float psum = 0.f;
  #pragma unroll
  for (int tn = 0; tn < 11; ++tn) {
    int col = tn * 16 + coll;
    bool valid = col < NREAL;
    float bx = valid ? b_x[col] : 0.f;
    #pragma unroll
    for (int tm = 0; tm < 2; ++tm)
      #pragma unroll
      for (int r = 0; r < 4; ++r) {
        float p = valid ? expf(acc[tm][tn][r] + bx) : 0.f;
        acc[tm][tn][r] = p;
        psum += p;
      }
  }
  #pragma unroll
  for (int off = 32; off; off >>= 1) psum += __shfl_xor(psum, off);
  float Xe = Xxe[g];
  float inv = 1.0f / (psum + Xe);
  if (lane == 0) outE[g] = Xe * inv;

  #pragma unroll
  for (int tn = 0; tn < 11; ++tn) {
    int col = tn * 16 + coll;
    if (col >= NREAL) continue;
    #pragma unroll
    for (int tm = 0; tm < 2; ++tm)
      #pragma unroll
      for (int r = 0; r < 4; ++r) {
        long row = baseRow + w * 32 + tm * 16 + rowq + r;
        float v = acc[tm][tn][r] * inv;
        if (col >= 4) outA[row * 160 + (col - 4)] = v;
        else          outC[row * 4 + col] = v;
      }
  }
}

extern "C" void kernel_launch(void* const* d_in, const int* in_sizes, int n_in,
                              void* d_out, int out_size, void* d_ws, size_t ws_size,
                              hipStream_t stream)
{
  const float* X    = (const float*)d_in[0];
  const int*   NX   = (const int*)d_in[1];      // int64 in ref -> int32 in harness
  const float* W_h  = (const float*)d_in[3];
  const float* g_h  = (const float*)d_in[4];
  const float* b_h  = (const float*)d_in[5];
  const float* W_ht = (const float*)d_in[6];
  const float* g_ht = (const float*)d_in[7];
  const float* b_ht = (const float*)d_in[8];
  const float* W_x  = (const float*)d_in[9];
  const float* b_x  = (const float*)d_in[10];
  const float* W_xt = (const float*)d_in[11];
  const float* b_xt = (const float*)d_in[12];

  char* ws = (char*)d_ws;
  bf16*  Xb    = (bf16*)(ws + OFF_XB);
  bf16*  X_endb= (bf16*)(ws + OFF_XENDB);
  bf16*  W1a   = (bf16*)(ws + OFF_W1A);
  bf16*  Bcat  = (bf16*)(ws + OFF_BCAT);
  bf16*  Wxb   = (bf16*)(ws + OFF_WXB);
  float* stats = (float*)(ws + OFF_STATS);
  float* s1m = stats, *s2m = stats + 512, *s1e = stats + 1024, *s2e = stats + 1536;
  float* Xxe   = (float*)(ws + OFF_XXE);
  float* Ccat  = (float*)(ws + OFF_CCAT);
  bf16*  H     = (bf16*)(ws + OFF_H);

  float* outA = (float*)d_out;                 // append: 131072*160
  float* outC = outA + (long)N_NODES * 160;    // connect: 131072*4
  float* outE = outC + (long)N_NODES * 4;      // end: 4096

  k_wcast<<<1024, 256, 0, stream>>>(W_h, W_ht, W_x, W1a, Bcat, Wxb, stats);
  k_xend<<<N_GRAPHS, 256, 0, stream>>>(X, NX, Xb, X_endb);
  gemm0<<<256, 256, 0, stream>>>(X_endb, Bcat, Ccat, s1e, s2e);
  k_xxend<<<1024, 256, 0, stream>>>(Ccat, s1e, s2e, g_ht, b_ht, W_xt, b_xt, Xxe);
  gemm1<<<256, 512, 0, stream>>>(Xb, W1a, Ccat, H, s1m, s2m);
  gemm2<<<1024, 256, 0, stream>>>(H, Wxb, s1m, s2m, g_h, b_h, b_x, Xxe, outA, outC, outE);
}